// Round 3
// baseline (212.621 us; speedup 1.0000x reference)
//
#include <hip/hip_runtime.h>
#include <math.h>

#define NATOMS 128
#define NALIGN 64
#define FPB    32     // frames per block
#define TPB    256

typedef float nfloat4 __attribute__((ext_vector_type(4)));  // native vec for nontemporal builtin

// Jacobi rotation on symmetric 3x3 for pair (p,q); third index r.
#define JACOBI_ROT(app, aqq, apq, arp, arq, pcol, qcol)                 \
  {                                                                     \
    float _apq = (apq);                                                 \
    if (fabsf(_apq) > 1e-20f) {                                         \
      float _tau = ((aqq) - (app)) / (2.0f * _apq);                     \
      float _t = (_tau >= 0.0f ? 1.0f : -1.0f) /                        \
                 (fabsf(_tau) + sqrtf(1.0f + _tau * _tau));             \
      float _c = rsqrtf(1.0f + _t * _t);                                \
      float _s = _t * _c;                                               \
      (app) -= _t * _apq;                                               \
      (aqq) += _t * _apq;                                               \
      (apq) = 0.0f;                                                     \
      float _rp = (arp), _rq = (arq);                                   \
      (arp) = _c * _rp - _s * _rq;                                      \
      (arq) = _s * _rp + _c * _rq;                                      \
      _Pragma("unroll")                                                 \
      for (int _r = 0; _r < 3; _r++) {                                  \
        float _vp = v[3 * _r + (pcol)], _vq = v[3 * _r + (qcol)];       \
        v[3 * _r + (pcol)] = _c * _vp - _s * _vq;                       \
        v[3 * _r + (qcol)] = _s * _vp + _c * _vq;                       \
      }                                                                 \
    }                                                                   \
  }

__global__ __launch_bounds__(TPB) void align_kernel(
    const float* __restrict__ traj,
    const float* __restrict__ ref_pos,
    const int* __restrict__ align_idx,
    float* __restrict__ out,
    int B)
{
    // wref[a] = centered ref vector for atom a if selected (w=1), else 0.
    __shared__ float4 s_wref[NATOMS];
    __shared__ __align__(16) float s_mat[FPB][12];   // cov(9)+xc(3) -> R(9)+xc(3)

    const int t  = threadIdx.x;
    const int f0 = blockIdx.x * FPB;
    const int r  = t & 31;        // atom-group (4 atoms) within frame
    const int fg = t >> 5;        // frame sub-group 0..7

    // ---------- Issue ALL traj loads up front (coalesced float4, deep MLP) ----
    float4 q[4][3];
    int gfv[4];
    #pragma unroll
    for (int i = 0; i < 4; i++) {
        int gf = f0 + i * 8 + fg;
        gfv[i] = gf;
        if (gf < B) {
            const float* p = traj + (size_t)gf * (NATOMS * 3) + r * 12;
            q[i][0] = *(const float4*)(p);
            q[i][1] = *(const float4*)(p + 4);
            q[i][2] = *(const float4*)(p + 8);
        } else {
            q[i][0] = q[i][1] = q[i][2] = make_float4(0.f, 0.f, 0.f, 0.f);
        }
    }

    // ---------- Stage 0: build weighted centered-ref table ----------
    if (t < NATOMS) s_wref[t] = make_float4(0.f, 0.f, 0.f, 0.f);
    __syncthreads();
    if (t < NALIGN) {
        int idx = align_idx[t];
        float rx = ref_pos[idx * 3 + 0];
        float ry = ref_pos[idx * 3 + 1];
        float rz = ref_pos[idx * 3 + 2];
        float sx = rx, sy = ry, sz = rz;
        #pragma unroll
        for (int off = 32; off >= 1; off >>= 1) {
            sx += __shfl_xor(sx, off);
            sy += __shfl_xor(sy, off);
            sz += __shfl_xor(sz, off);
        }
        const float inv = 1.0f / (float)NALIGN;
        s_wref[idx] = make_float4(rx - sx * inv, ry - sy * inv, rz - sz * inv, 1.0f);
    }
    __syncthreads();

    // ---------- Stage 1: covariance + centroid from register data ----------
    // cov[i][j] = sum_sel x_i * refc_j  (valid since sum refc = 0)
    #pragma unroll
    for (int i = 0; i < 4; i++) {
        float sx = 0.f, sy = 0.f, sz = 0.f;
        float c[9] = {0.f,0.f,0.f,0.f,0.f,0.f,0.f,0.f,0.f};
        // unpack 4 atoms from 3 float4s
        float ax[4], ay[4], az[4];
        ax[0]=q[i][0].x; ay[0]=q[i][0].y; az[0]=q[i][0].z;
        ax[1]=q[i][0].w; ay[1]=q[i][1].x; az[1]=q[i][1].y;
        ax[2]=q[i][1].z; ay[2]=q[i][1].w; az[2]=q[i][2].x;
        ax[3]=q[i][2].y; ay[3]=q[i][2].z; az[3]=q[i][2].w;
        #pragma unroll
        for (int k = 0; k < 4; k++) {
            float4 wr = s_wref[r * 4 + k];
            float x = ax[k], y = ay[k], z = az[k];
            sx += wr.w * x; sy += wr.w * y; sz += wr.w * z;
            c[0] += x * wr.x; c[1] += x * wr.y; c[2] += x * wr.z;
            c[3] += y * wr.x; c[4] += y * wr.y; c[5] += y * wr.z;
            c[6] += z * wr.x; c[7] += z * wr.y; c[8] += z * wr.z;
        }
        // butterfly-reduce 12 values over the 32-lane frame group
        #pragma unroll
        for (int off = 16; off >= 1; off >>= 1) {
            sx += __shfl_xor(sx, off);
            sy += __shfl_xor(sy, off);
            sz += __shfl_xor(sz, off);
            #pragma unroll
            for (int j = 0; j < 9; j++) c[j] += __shfl_xor(c[j], off);
        }
        if (r == 0 && gfv[i] < B) {
            int f = i * 8 + fg;
            #pragma unroll
            for (int j = 0; j < 9; j++) s_mat[f][j] = c[j];
            const float inv = 1.0f / (float)NALIGN;
            s_mat[f][9]  = sx * inv;
            s_mat[f][10] = sy * inv;
            s_mat[f][11] = sz * inv;
        }
    }
    __syncthreads();

    // ---------- Stage 2: 3x3 SVD -> rotation (one lane per frame) ----------
    if (t < FPB && (f0 + t) < B) {
        float m[9];
        #pragma unroll
        for (int j = 0; j < 9; j++) m[j] = s_mat[t][j];

        float a00 = m[0]*m[0] + m[3]*m[3] + m[6]*m[6];
        float a01 = m[0]*m[1] + m[3]*m[4] + m[6]*m[7];
        float a02 = m[0]*m[2] + m[3]*m[5] + m[6]*m[8];
        float a11 = m[1]*m[1] + m[4]*m[4] + m[7]*m[7];
        float a12 = m[1]*m[2] + m[4]*m[5] + m[7]*m[8];
        float a22 = m[2]*m[2] + m[5]*m[5] + m[8]*m[8];

        float v[9] = {1.f,0.f,0.f, 0.f,1.f,0.f, 0.f,0.f,1.f};
        #pragma unroll
        for (int sweep = 0; sweep < 5; sweep++) {
            JACOBI_ROT(a00, a11, a01, a02, a12, 0, 1);
            JACOBI_ROT(a00, a22, a02, a01, a12, 0, 2);
            JACOBI_ROT(a11, a22, a12, a01, a02, 1, 2);
        }

        float dd[3] = {a00, a11, a22};
        #pragma unroll
        for (int pass = 0; pass < 3; pass++) {
            int ii = (pass == 0) ? 0 : (pass == 1) ? 0 : 1;
            int jj = (pass == 0) ? 1 : 2;
            if (dd[ii] < dd[jj]) {
                float tmp = dd[ii]; dd[ii] = dd[jj]; dd[jj] = tmp;
                #pragma unroll
                for (int rr = 0; rr < 3; rr++) {
                    float tv = v[3*rr+ii]; v[3*rr+ii] = v[3*rr+jj]; v[3*rr+jj] = tv;
                }
            }
        }

        float v0x = v[0], v0y = v[3], v0z = v[6];
        float v1x = v[1], v1y = v[4], v1z = v[7];
        float v2x = v[2], v2y = v[5], v2z = v[8];

        float u1x = m[0]*v0x + m[1]*v0y + m[2]*v0z;
        float u1y = m[3]*v0x + m[4]*v0y + m[5]*v0z;
        float u1z = m[6]*v0x + m[7]*v0y + m[8]*v0z;
        float n1 = rsqrtf(fmaxf(u1x*u1x + u1y*u1y + u1z*u1z, 1e-30f));
        u1x *= n1; u1y *= n1; u1z *= n1;

        float u2x = m[0]*v1x + m[1]*v1y + m[2]*v1z;
        float u2y = m[3]*v1x + m[4]*v1y + m[5]*v1z;
        float u2z = m[6]*v1x + m[7]*v1y + m[8]*v1z;
        float d12 = u1x*u2x + u1y*u2y + u1z*u2z;
        u2x -= d12 * u1x; u2y -= d12 * u1y; u2z -= d12 * u1z;
        float n2 = rsqrtf(fmaxf(u2x*u2x + u2y*u2y + u2z*u2z, 1e-30f));
        u2x *= n2; u2y *= n2; u2z *= n2;

        float u3x = u1y*u2z - u1z*u2y;
        float u3y = u1z*u2x - u1x*u2z;
        float u3z = u1x*u2y - u1y*u2x;
        float cx = v1y*v2z - v1z*v2y;
        float cy = v1z*v2x - v1x*v2z;
        float cz = v1x*v2y - v1y*v2x;
        float detv = v0x*cx + v0y*cy + v0z*cz;
        float sg = (detv >= 0.f) ? 1.f : -1.f;
        u3x *= sg; u3y *= sg; u3z *= sg;

        s_mat[t][0] = u1x*v0x + u2x*v1x + u3x*v2x;
        s_mat[t][1] = u1x*v0y + u2x*v1y + u3x*v2y;
        s_mat[t][2] = u1x*v0z + u2x*v1z + u3x*v2z;
        s_mat[t][3] = u1y*v0x + u2y*v1x + u3y*v2x;
        s_mat[t][4] = u1y*v0y + u2y*v1y + u3y*v2y;
        s_mat[t][5] = u1y*v0z + u2y*v1z + u3y*v2z;
        s_mat[t][6] = u1z*v0x + u2z*v1x + u3z*v2x;
        s_mat[t][7] = u1z*v0y + u2z*v1y + u3z*v2y;
        s_mat[t][8] = u1z*v0z + u2z*v1z + u3z*v2z;
        // [9..11] keeps xc
    }
    __syncthreads();

    // ---------- Stage 3: apply rotation to register data, stream out ----------
    #pragma unroll
    for (int i = 0; i < 4; i++) {
        int gf = gfv[i];
        if (gf < B) {
            int f = i * 8 + fg;
            float4 Ra = *(const float4*)&s_mat[f][0];   // R0 R1 R2 R3
            float4 Rb = *(const float4*)&s_mat[f][4];   // R4 R5 R6 R7
            float4 Rc = *(const float4*)&s_mat[f][8];   // R8 xcx xcy xcz
            float R0 = Ra.x, R1 = Ra.y, R2 = Ra.z, R3 = Ra.w;
            float R4 = Rb.x, R5 = Rb.y, R6 = Rb.z, R7 = Rb.w;
            float R8 = Rc.x, xcx = Rc.y, xcy = Rc.z, xcz = Rc.w;

            float4 q0 = q[i][0], q1 = q[i][1], q2 = q[i][2];
            float dx, dy, dz;
            dx = q0.x - xcx; dy = q0.y - xcy; dz = q0.z - xcz;
            float o0x = dx*R0 + dy*R3 + dz*R6;
            float o0y = dx*R1 + dy*R4 + dz*R7;
            float o0z = dx*R2 + dy*R5 + dz*R8;
            dx = q0.w - xcx; dy = q1.x - xcy; dz = q1.y - xcz;
            float o1x = dx*R0 + dy*R3 + dz*R6;
            float o1y = dx*R1 + dy*R4 + dz*R7;
            float o1z = dx*R2 + dy*R5 + dz*R8;
            dx = q1.z - xcx; dy = q1.w - xcy; dz = q2.x - xcz;
            float o2x = dx*R0 + dy*R3 + dz*R6;
            float o2y = dx*R1 + dy*R4 + dz*R7;
            float o2z = dx*R2 + dy*R5 + dz*R8;
            dx = q2.y - xcx; dy = q2.z - xcy; dz = q2.w - xcz;
            float o3x = dx*R0 + dy*R3 + dz*R6;
            float o3y = dx*R1 + dy*R4 + dz*R7;
            float o3z = dx*R2 + dy*R5 + dz*R8;

            float* po = out + (size_t)gf * (NATOMS * 3) + r * 12;
            nfloat4 w0 = {o0x, o0y, o0z, o1x};
            nfloat4 w1 = {o1y, o1z, o2x, o2y};
            nfloat4 w2 = {o2z, o3x, o3y, o3z};
            __builtin_nontemporal_store(w0, (nfloat4*)(po));
            __builtin_nontemporal_store(w1, (nfloat4*)(po + 4));
            __builtin_nontemporal_store(w2, (nfloat4*)(po + 8));
        }
    }
}

extern "C" void kernel_launch(void* const* d_in, const int* in_sizes, int n_in,
                              void* d_out, int out_size, void* d_ws, size_t ws_size,
                              hipStream_t stream) {
    const float* traj      = (const float*)d_in[0];
    const float* ref_pos   = (const float*)d_in[1];
    const int*   align_idx = (const int*)d_in[2];
    float*       out       = (float*)d_out;

    int B = in_sizes[0] / (NATOMS * 3);
    int grid = (B + FPB - 1) / FPB;
    align_kernel<<<grid, TPB, 0, stream>>>(traj, ref_pos, align_idx, out, B);
}

// Round 4
// 210.675 us; speedup vs baseline: 1.0092x; 1.0092x over previous
//
#include <hip/hip_runtime.h>
#include <math.h>

#define NATOMS 128
#define NALIGN 64
#define FPB    32     // frames per block (kernel 1)
#define TPB    256
#define FSTRIDE 97    // padded frame stride in float4 units (96 data + 1 pad)

// Jacobi rotation on symmetric 3x3 for pair (p,q); third index r.
#define JACOBI_ROT(app, aqq, apq, arp, arq, pcol, qcol)                 \
  {                                                                     \
    float _apq = (apq);                                                 \
    if (fabsf(_apq) > 1e-20f) {                                         \
      float _tau = ((aqq) - (app)) / (2.0f * _apq);                     \
      float _t = (_tau >= 0.0f ? 1.0f : -1.0f) /                        \
                 (fabsf(_tau) + sqrtf(1.0f + _tau * _tau));             \
      float _c = rsqrtf(1.0f + _t * _t);                                \
      float _s = _t * _c;                                               \
      (app) -= _t * _apq;                                               \
      (aqq) += _t * _apq;                                               \
      (apq) = 0.0f;                                                     \
      float _rp = (arp), _rq = (arq);                                   \
      (arp) = _c * _rp - _s * _rq;                                      \
      (arq) = _s * _rp + _c * _rq;                                      \
      _Pragma("unroll")                                                 \
      for (int _r = 0; _r < 3; _r++) {                                  \
        float _vp = v[3 * _r + (pcol)], _vq = v[3 * _r + (qcol)];       \
        v[3 * _r + (pcol)] = _c * _vp - _s * _vq;                       \
        v[3 * _r + (qcol)] = _s * _vp + _c * _vq;                       \
      }                                                                 \
    }                                                                   \
  }

// ======================= Kernel 1: covariance + SVD -> R ====================
__global__ __launch_bounds__(TPB) void compute_R_kernel(
    const float* __restrict__ traj,
    const float* __restrict__ ref_pos,
    const int* __restrict__ align_idx,
    float* __restrict__ ws,      // [B][12] = R(9), xc(3)
    int B)
{
    __shared__ float4 s_traj[FPB * FSTRIDE];   // padded frames, 49.7 KB
    __shared__ float4 s_ref[NALIGN];
    __shared__ int    s_idx[NALIGN];
    __shared__ __align__(16) float s_mat[FPB][12];

    const int t  = threadIdx.x;
    const int f0 = blockIdx.x * FPB;

    // ---- stage 0: center reference (wave 0) ----
    if (t < NALIGN) {
        int idx = align_idx[t];
        s_idx[t] = idx;
        float rx = ref_pos[idx * 3 + 0];
        float ry = ref_pos[idx * 3 + 1];
        float rz = ref_pos[idx * 3 + 2];
        float sx = rx, sy = ry, sz = rz;
        #pragma unroll
        for (int off = 32; off >= 1; off >>= 1) {
            sx += __shfl_xor(sx, off);
            sy += __shfl_xor(sy, off);
            sz += __shfl_xor(sz, off);
        }
        const float inv = 1.0f / (float)NALIGN;
        s_ref[t] = make_float4(rx - sx * inv, ry - sy * inv, rz - sz * inv, 0.0f);
    }

    // ---- stage A: coalesced staging of 32 frames into padded LDS ----
    const float4* g4 = (const float4*)traj + (size_t)f0 * 96;
    #pragma unroll
    for (int k = 0; k < 12; k++) {
        int j = k * TPB + t;               // 0..3071 float4 within block tile
        int f = j / 96;
        int p = j - f * 96;
        if (f0 + f < B) {
            s_traj[f * FSTRIDE + p] = g4[j];
        }
    }
    __syncthreads();

    // ---- stage B: gather selected atoms from LDS, centroid + covariance ----
    {
        const int f   = t >> 3;            // local frame 0..31
        const int sub = t & 7;             // 8 lanes per frame
        const int gf  = f0 + f;
        if (gf < B) {
            const float* fr = (const float*)&s_traj[f * FSTRIDE];
            float px[8], py[8], pz[8];
            float sx = 0.f, sy = 0.f, sz = 0.f;
            #pragma unroll
            for (int i = 0; i < 8; i++) {
                int a   = sub + 8 * i;
                int idx = s_idx[a];
                float x = fr[idx * 3 + 0];
                float y = fr[idx * 3 + 1];
                float z = fr[idx * 3 + 2];
                px[i] = x; py[i] = y; pz[i] = z;
                sx += x; sy += y; sz += z;
            }
            #pragma unroll
            for (int off = 4; off >= 1; off >>= 1) {
                sx += __shfl_xor(sx, off);
                sy += __shfl_xor(sy, off);
                sz += __shfl_xor(sz, off);
            }
            const float inv = 1.0f / (float)NALIGN;
            float xcx = sx * inv, xcy = sy * inv, xcz = sz * inv;

            float c[9] = {0.f,0.f,0.f,0.f,0.f,0.f,0.f,0.f,0.f};
            #pragma unroll
            for (int i = 0; i < 8; i++) {
                int a = sub + 8 * i;
                float4 r = s_ref[a];       // same addr across frames -> broadcast
                float dx = px[i] - xcx, dy = py[i] - xcy, dz = pz[i] - xcz;
                c[0] += dx * r.x; c[1] += dx * r.y; c[2] += dx * r.z;
                c[3] += dy * r.x; c[4] += dy * r.y; c[5] += dy * r.z;
                c[6] += dz * r.x; c[7] += dz * r.y; c[8] += dz * r.z;
            }
            #pragma unroll
            for (int off = 4; off >= 1; off >>= 1) {
                #pragma unroll
                for (int j = 0; j < 9; j++) c[j] += __shfl_xor(c[j], off);
            }
            if (sub == 0) {
                #pragma unroll
                for (int j = 0; j < 9; j++) s_mat[f][j] = c[j];
                s_mat[f][9]  = xcx;
                s_mat[f][10] = xcy;
                s_mat[f][11] = xcz;
            }
        }
    }
    __syncthreads();

    // ---- stage C: 3x3 SVD -> rotation (one lane per frame), write ws ----
    if (t < FPB && (f0 + t) < B) {
        float m[9];
        #pragma unroll
        for (int j = 0; j < 9; j++) m[j] = s_mat[t][j];

        float a00 = m[0]*m[0] + m[3]*m[3] + m[6]*m[6];
        float a01 = m[0]*m[1] + m[3]*m[4] + m[6]*m[7];
        float a02 = m[0]*m[2] + m[3]*m[5] + m[6]*m[8];
        float a11 = m[1]*m[1] + m[4]*m[4] + m[7]*m[7];
        float a12 = m[1]*m[2] + m[4]*m[5] + m[7]*m[8];
        float a22 = m[2]*m[2] + m[5]*m[5] + m[8]*m[8];

        float v[9] = {1.f,0.f,0.f, 0.f,1.f,0.f, 0.f,0.f,1.f};
        #pragma unroll
        for (int sweep = 0; sweep < 5; sweep++) {
            JACOBI_ROT(a00, a11, a01, a02, a12, 0, 1);
            JACOBI_ROT(a00, a22, a02, a01, a12, 0, 2);
            JACOBI_ROT(a11, a22, a12, a01, a02, 1, 2);
        }

        float dd[3] = {a00, a11, a22};
        #pragma unroll
        for (int pass = 0; pass < 3; pass++) {
            int ii = (pass == 0) ? 0 : (pass == 1) ? 0 : 1;
            int jj = (pass == 0) ? 1 : 2;
            if (dd[ii] < dd[jj]) {
                float tmp = dd[ii]; dd[ii] = dd[jj]; dd[jj] = tmp;
                #pragma unroll
                for (int rr = 0; rr < 3; rr++) {
                    float tv = v[3*rr+ii]; v[3*rr+ii] = v[3*rr+jj]; v[3*rr+jj] = tv;
                }
            }
        }

        float v0x = v[0], v0y = v[3], v0z = v[6];
        float v1x = v[1], v1y = v[4], v1z = v[7];
        float v2x = v[2], v2y = v[5], v2z = v[8];

        float u1x = m[0]*v0x + m[1]*v0y + m[2]*v0z;
        float u1y = m[3]*v0x + m[4]*v0y + m[5]*v0z;
        float u1z = m[6]*v0x + m[7]*v0y + m[8]*v0z;
        float n1 = rsqrtf(fmaxf(u1x*u1x + u1y*u1y + u1z*u1z, 1e-30f));
        u1x *= n1; u1y *= n1; u1z *= n1;

        float u2x = m[0]*v1x + m[1]*v1y + m[2]*v1z;
        float u2y = m[3]*v1x + m[4]*v1y + m[5]*v1z;
        float u2z = m[6]*v1x + m[7]*v1y + m[8]*v1z;
        float d12 = u1x*u2x + u1y*u2y + u1z*u2z;
        u2x -= d12 * u1x; u2y -= d12 * u1y; u2z -= d12 * u1z;
        float n2 = rsqrtf(fmaxf(u2x*u2x + u2y*u2y + u2z*u2z, 1e-30f));
        u2x *= n2; u2y *= n2; u2z *= n2;

        float u3x = u1y*u2z - u1z*u2y;
        float u3y = u1z*u2x - u1x*u2z;
        float u3z = u1x*u2y - u1y*u2x;
        float cx = v1y*v2z - v1z*v2y;
        float cy = v1z*v2x - v1x*v2z;
        float cz = v1x*v2y - v1y*v2x;
        float detv = v0x*cx + v0y*cy + v0z*cz;
        float sg = (detv >= 0.f) ? 1.f : -1.f;
        u3x *= sg; u3y *= sg; u3z *= sg;

        float R0 = u1x*v0x + u2x*v1x + u3x*v2x;
        float R1 = u1x*v0y + u2x*v1y + u3x*v2y;
        float R2 = u1x*v0z + u2x*v1z + u3x*v2z;
        float R3 = u1y*v0x + u2y*v1x + u3y*v2x;
        float R4 = u1y*v0y + u2y*v1y + u3y*v2y;
        float R5 = u1y*v0z + u2y*v1z + u3y*v2z;
        float R6 = u1z*v0x + u2z*v1x + u3z*v2x;
        float R7 = u1z*v0y + u2z*v1y + u3z*v2y;
        float R8 = u1z*v0z + u2z*v1z + u3z*v2z;

        float4* w4 = (float4*)ws + (size_t)(f0 + t) * 3;
        w4[0] = make_float4(R0, R1, R2, R3);
        w4[1] = make_float4(R4, R5, R6, R7);
        w4[2] = make_float4(R8, s_mat[t][9], s_mat[t][10], s_mat[t][11]);
    }
}

// ======================= Kernel 2: apply rotation (streaming) ===============
// One block = 8 frames = 768 float4. LDS bounce makes every global access
// contiguous per instruction; regular stores let L2 assemble full lines.
__global__ __launch_bounds__(TPB) void apply_kernel(
    const float* __restrict__ traj,
    const float* __restrict__ ws,
    float* __restrict__ out,
    int B)
{
    __shared__ float4 s_buf[8 * FSTRIDE];   // 776 float4 = 12.4 KB
    __shared__ float  s_R[8 * 12];

    const int t = threadIdx.x;
    const size_t tile = blockIdx.x;
    const int fbase = (int)tile * 8;
    const float4* in4 = (const float4*)traj + tile * 768;
    float4* out4 = (float4*)out + tile * 768;

    // phase 1: coalesced load -> padded LDS; also load 8 R-matrices
    if (t < 96) {
        int f = t / 12;
        if (fbase + f < B) s_R[t] = ws[(size_t)(fbase) * 12 + t];
    }
    #pragma unroll
    for (int k = 0; k < 3; k++) {
        int j = k * TPB + t;           // 0..767
        int f = j / 96;
        int p = j - f * 96;
        if (fbase + f < B) s_buf[f * FSTRIDE + p] = in4[j];
    }
    __syncthreads();

    // phase 2: each thread rotates 4 atoms (3 float4) of its frame, in place
    {
        const int f = t >> 5;          // 0..7
        const int r = t & 31;
        if (fbase + f < B) {
            float4 q0 = s_buf[f * FSTRIDE + 3 * r + 0];
            float4 q1 = s_buf[f * FSTRIDE + 3 * r + 1];
            float4 q2 = s_buf[f * FSTRIDE + 3 * r + 2];

            const float* Rp = &s_R[f * 12];   // broadcast reads
            float R0 = Rp[0], R1 = Rp[1], R2 = Rp[2], R3 = Rp[3];
            float R4 = Rp[4], R5 = Rp[5], R6 = Rp[6], R7 = Rp[7];
            float R8 = Rp[8], xcx = Rp[9], xcy = Rp[10], xcz = Rp[11];

            float dx, dy, dz;
            dx = q0.x - xcx; dy = q0.y - xcy; dz = q0.z - xcz;
            float o0x = dx*R0 + dy*R3 + dz*R6;
            float o0y = dx*R1 + dy*R4 + dz*R7;
            float o0z = dx*R2 + dy*R5 + dz*R8;
            dx = q0.w - xcx; dy = q1.x - xcy; dz = q1.y - xcz;
            float o1x = dx*R0 + dy*R3 + dz*R6;
            float o1y = dx*R1 + dy*R4 + dz*R7;
            float o1z = dx*R2 + dy*R5 + dz*R8;
            dx = q1.z - xcx; dy = q1.w - xcy; dz = q2.x - xcz;
            float o2x = dx*R0 + dy*R3 + dz*R6;
            float o2y = dx*R1 + dy*R4 + dz*R7;
            float o2z = dx*R2 + dy*R5 + dz*R8;
            dx = q2.y - xcx; dy = q2.z - xcy; dz = q2.w - xcz;
            float o3x = dx*R0 + dy*R3 + dz*R6;
            float o3y = dx*R1 + dy*R4 + dz*R7;
            float o3z = dx*R2 + dy*R5 + dz*R8;

            s_buf[f * FSTRIDE + 3 * r + 0] = make_float4(o0x, o0y, o0z, o1x);
            s_buf[f * FSTRIDE + 3 * r + 1] = make_float4(o1y, o1z, o2x, o2y);
            s_buf[f * FSTRIDE + 3 * r + 2] = make_float4(o2z, o3x, o3y, o3z);
        }
    }
    __syncthreads();

    // phase 3: coalesced store
    #pragma unroll
    for (int k = 0; k < 3; k++) {
        int j = k * TPB + t;
        int f = j / 96;
        int p = j - f * 96;
        if (fbase + f < B) out4[j] = s_buf[f * FSTRIDE + p];
    }
}

extern "C" void kernel_launch(void* const* d_in, const int* in_sizes, int n_in,
                              void* d_out, int out_size, void* d_ws, size_t ws_size,
                              hipStream_t stream) {
    const float* traj      = (const float*)d_in[0];
    const float* ref_pos   = (const float*)d_in[1];
    const int*   align_idx = (const int*)d_in[2];
    float*       out       = (float*)d_out;
    float*       ws        = (float*)d_ws;

    int B = in_sizes[0] / (NATOMS * 3);
    int grid1 = (B + FPB - 1) / FPB;
    compute_R_kernel<<<grid1, TPB, 0, stream>>>(traj, ref_pos, align_idx, ws, B);
    int grid2 = (B + 7) / 8;
    apply_kernel<<<grid2, TPB, 0, stream>>>(traj, ws, out, B);
}

// Round 5
// 199.072 us; speedup vs baseline: 1.0681x; 1.0583x over previous
//
#include <hip/hip_runtime.h>
#include <math.h>

#define NATOMS 128
#define NALIGN 64
#define FPB    16     // frames per block
#define TPB    256
#define FSTRIDE 97    // padded frame stride in float4 units (96 data + 1 pad)

// Jacobi rotation on symmetric 3x3 for pair (p,q); third index r.
#define JACOBI_ROT(app, aqq, apq, arp, arq, pcol, qcol)                 \
  {                                                                     \
    float _apq = (apq);                                                 \
    if (fabsf(_apq) > 1e-20f) {                                         \
      float _tau = ((aqq) - (app)) / (2.0f * _apq);                     \
      float _t = (_tau >= 0.0f ? 1.0f : -1.0f) /                        \
                 (fabsf(_tau) + sqrtf(1.0f + _tau * _tau));             \
      float _c = rsqrtf(1.0f + _t * _t);                                \
      float _s = _t * _c;                                               \
      (app) -= _t * _apq;                                               \
      (aqq) += _t * _apq;                                               \
      (apq) = 0.0f;                                                     \
      float _rp = (arp), _rq = (arq);                                   \
      (arp) = _c * _rp - _s * _rq;                                      \
      (arq) = _s * _rp + _c * _rq;                                      \
      _Pragma("unroll")                                                 \
      for (int _r = 0; _r < 3; _r++) {                                  \
        float _vp = v[3 * _r + (pcol)], _vq = v[3 * _r + (qcol)];       \
        v[3 * _r + (pcol)] = _c * _vp - _s * _vq;                       \
        v[3 * _r + (qcol)] = _s * _vp + _c * _vq;                       \
      }                                                                 \
    }                                                                   \
  }

__global__ __launch_bounds__(TPB) void align_kernel(
    const float* __restrict__ traj,
    const float* __restrict__ ref_pos,
    const int* __restrict__ align_idx,
    float* __restrict__ out,
    int B)
{
    __shared__ float4 s_traj[FPB * FSTRIDE];   // 16 padded frames, 24.8 KB
    __shared__ float4 s_ref[NALIGN];           // centered ref
    __shared__ int    s_idx[NALIGN];
    __shared__ __align__(16) float s_mat[FPB][12];  // cov(9)+xc(3) -> R(9)+xc(3)

    const int t  = threadIdx.x;
    const int f0 = blockIdx.x * FPB;

    // ---- stage 0: center reference (wave 0) ----
    if (t < NALIGN) {
        int idx = align_idx[t];
        s_idx[t] = idx;
        float rx = ref_pos[idx * 3 + 0];
        float ry = ref_pos[idx * 3 + 1];
        float rz = ref_pos[idx * 3 + 2];
        float sx = rx, sy = ry, sz = rz;
        #pragma unroll
        for (int off = 32; off >= 1; off >>= 1) {
            sx += __shfl_xor(sx, off);
            sy += __shfl_xor(sy, off);
            sz += __shfl_xor(sz, off);
        }
        const float inv = 1.0f / (float)NALIGN;
        s_ref[t] = make_float4(rx - sx * inv, ry - sy * inv, rz - sz * inv, 0.0f);
    }

    // ---- stage A: coalesced staging of 16 frames into padded LDS ----
    const float4* g4 = (const float4*)traj + (size_t)f0 * 96;
    #pragma unroll
    for (int k = 0; k < 6; k++) {
        int j = k * TPB + t;               // 0..1535 float4 within block tile
        int f = j / 96;
        int p = j - f * 96;
        if (f0 + f < B) s_traj[f * FSTRIDE + p] = g4[j];
    }
    __syncthreads();

    // ---- stage B: covariance + centroid from LDS (16 lanes/frame) ----
    // cov[i][j] = sum_sel x_i * refc_j  (valid since sum refc = 0)
    {
        const int f   = t >> 4;            // local frame 0..15
        const int sub = t & 15;            // 16 lanes per frame
        const int gf  = f0 + f;
        if (gf < B) {
            const float* fr = (const float*)&s_traj[f * FSTRIDE];
            float sx = 0.f, sy = 0.f, sz = 0.f;
            float c[9] = {0.f,0.f,0.f,0.f,0.f,0.f,0.f,0.f,0.f};
            #pragma unroll
            for (int i = 0; i < 4; i++) {
                int a   = sub + 16 * i;
                int idx = s_idx[a];
                float x = fr[idx * 3 + 0];
                float y = fr[idx * 3 + 1];
                float z = fr[idx * 3 + 2];
                float4 rr = s_ref[a];      // 2 frames/wave share addr -> 2-way (free)
                sx += x; sy += y; sz += z;
                c[0] += x * rr.x; c[1] += x * rr.y; c[2] += x * rr.z;
                c[3] += y * rr.x; c[4] += y * rr.y; c[5] += y * rr.z;
                c[6] += z * rr.x; c[7] += z * rr.y; c[8] += z * rr.z;
            }
            // butterfly over the 16-lane frame group
            #pragma unroll
            for (int off = 8; off >= 1; off >>= 1) {
                sx += __shfl_xor(sx, off);
                sy += __shfl_xor(sy, off);
                sz += __shfl_xor(sz, off);
                #pragma unroll
                for (int j = 0; j < 9; j++) c[j] += __shfl_xor(c[j], off);
            }
            if (sub == 0) {
                #pragma unroll
                for (int j = 0; j < 9; j++) s_mat[f][j] = c[j];
                const float inv = 1.0f / (float)NALIGN;
                s_mat[f][9]  = sx * inv;
                s_mat[f][10] = sy * inv;
                s_mat[f][11] = sz * inv;
            }
        }
    }
    __syncthreads();

    // ---- stage C: 3x3 SVD -> rotation (one lane per frame) ----
    if (t < FPB && (f0 + t) < B) {
        float m[9];
        #pragma unroll
        for (int j = 0; j < 9; j++) m[j] = s_mat[t][j];

        float a00 = m[0]*m[0] + m[3]*m[3] + m[6]*m[6];
        float a01 = m[0]*m[1] + m[3]*m[4] + m[6]*m[7];
        float a02 = m[0]*m[2] + m[3]*m[5] + m[6]*m[8];
        float a11 = m[1]*m[1] + m[4]*m[4] + m[7]*m[7];
        float a12 = m[1]*m[2] + m[4]*m[5] + m[7]*m[8];
        float a22 = m[2]*m[2] + m[5]*m[5] + m[8]*m[8];

        float v[9] = {1.f,0.f,0.f, 0.f,1.f,0.f, 0.f,0.f,1.f};
        #pragma unroll
        for (int sweep = 0; sweep < 5; sweep++) {
            JACOBI_ROT(a00, a11, a01, a02, a12, 0, 1);
            JACOBI_ROT(a00, a22, a02, a01, a12, 0, 2);
            JACOBI_ROT(a11, a22, a12, a01, a02, 1, 2);
        }

        float dd[3] = {a00, a11, a22};
        #pragma unroll
        for (int pass = 0; pass < 3; pass++) {
            int ii = (pass == 0) ? 0 : (pass == 1) ? 0 : 1;
            int jj = (pass == 0) ? 1 : 2;
            if (dd[ii] < dd[jj]) {
                float tmp = dd[ii]; dd[ii] = dd[jj]; dd[jj] = tmp;
                #pragma unroll
                for (int rr = 0; rr < 3; rr++) {
                    float tv = v[3*rr+ii]; v[3*rr+ii] = v[3*rr+jj]; v[3*rr+jj] = tv;
                }
            }
        }

        float v0x = v[0], v0y = v[3], v0z = v[6];
        float v1x = v[1], v1y = v[4], v1z = v[7];
        float v2x = v[2], v2y = v[5], v2z = v[8];

        float u1x = m[0]*v0x + m[1]*v0y + m[2]*v0z;
        float u1y = m[3]*v0x + m[4]*v0y + m[5]*v0z;
        float u1z = m[6]*v0x + m[7]*v0y + m[8]*v0z;
        float n1 = rsqrtf(fmaxf(u1x*u1x + u1y*u1y + u1z*u1z, 1e-30f));
        u1x *= n1; u1y *= n1; u1z *= n1;

        float u2x = m[0]*v1x + m[1]*v1y + m[2]*v1z;
        float u2y = m[3]*v1x + m[4]*v1y + m[5]*v1z;
        float u2z = m[6]*v1x + m[7]*v1y + m[8]*v1z;
        float d12 = u1x*u2x + u1y*u2y + u1z*u2z;
        u2x -= d12 * u1x; u2y -= d12 * u1y; u2z -= d12 * u1z;
        float n2 = rsqrtf(fmaxf(u2x*u2x + u2y*u2y + u2z*u2z, 1e-30f));
        u2x *= n2; u2y *= n2; u2z *= n2;

        float u3x = u1y*u2z - u1z*u2y;
        float u3y = u1z*u2x - u1x*u2z;
        float u3z = u1x*u2y - u1y*u2x;
        float cx = v1y*v2z - v1z*v2y;
        float cy = v1z*v2x - v1x*v2z;
        float cz = v1x*v2y - v1y*v2x;
        float detv = v0x*cx + v0y*cy + v0z*cz;
        float sg = (detv >= 0.f) ? 1.f : -1.f;
        u3x *= sg; u3y *= sg; u3z *= sg;

        s_mat[t][0] = u1x*v0x + u2x*v1x + u3x*v2x;
        s_mat[t][1] = u1x*v0y + u2x*v1y + u3x*v2y;
        s_mat[t][2] = u1x*v0z + u2x*v1z + u3x*v2z;
        s_mat[t][3] = u1y*v0x + u2y*v1x + u3y*v2x;
        s_mat[t][4] = u1y*v0y + u2y*v1y + u3y*v2y;
        s_mat[t][5] = u1y*v0z + u2y*v1z + u3y*v2z;
        s_mat[t][6] = u1z*v0x + u2z*v1x + u3z*v2x;
        s_mat[t][7] = u1z*v0y + u2z*v1y + u3z*v2y;
        s_mat[t][8] = u1z*v0z + u2z*v1z + u3z*v2z;
        // [9..11] keeps xc
    }
    __syncthreads();

    // ---- stage D: apply rotation from LDS copy, regular coalesced-ish stores ----
    #pragma unroll
    for (int w = 0; w < 2; w++) {
        int j  = w * TPB + t;          // 0..511 atom-groups (4 atoms each)
        int f  = j >> 5;               // local frame
        int r  = j & 31;               // group within frame
        int gf = f0 + f;
        if (gf < B) {
            float4 q0 = s_traj[f * FSTRIDE + 3 * r + 0];
            float4 q1 = s_traj[f * FSTRIDE + 3 * r + 1];
            float4 q2 = s_traj[f * FSTRIDE + 3 * r + 2];

            float4 Ra = *(const float4*)&s_mat[f][0];
            float4 Rb = *(const float4*)&s_mat[f][4];
            float4 Rc = *(const float4*)&s_mat[f][8];
            float R0 = Ra.x, R1 = Ra.y, R2 = Ra.z, R3 = Ra.w;
            float R4 = Rb.x, R5 = Rb.y, R6 = Rb.z, R7 = Rb.w;
            float R8 = Rc.x, xcx = Rc.y, xcy = Rc.z, xcz = Rc.w;

            float dx, dy, dz;
            dx = q0.x - xcx; dy = q0.y - xcy; dz = q0.z - xcz;
            float o0x = dx*R0 + dy*R3 + dz*R6;
            float o0y = dx*R1 + dy*R4 + dz*R7;
            float o0z = dx*R2 + dy*R5 + dz*R8;
            dx = q0.w - xcx; dy = q1.x - xcy; dz = q1.y - xcz;
            float o1x = dx*R0 + dy*R3 + dz*R6;
            float o1y = dx*R1 + dy*R4 + dz*R7;
            float o1z = dx*R2 + dy*R5 + dz*R8;
            dx = q1.z - xcx; dy = q1.w - xcy; dz = q2.x - xcz;
            float o2x = dx*R0 + dy*R3 + dz*R6;
            float o2y = dx*R1 + dy*R4 + dz*R7;
            float o2z = dx*R2 + dy*R5 + dz*R8;
            dx = q2.y - xcx; dy = q2.z - xcy; dz = q2.w - xcz;
            float o3x = dx*R0 + dy*R3 + dz*R6;
            float o3y = dx*R1 + dy*R4 + dz*R7;
            float o3z = dx*R2 + dy*R5 + dz*R8;

            float* po = out + (size_t)gf * (NATOMS * 3) + r * 12;
            *(float4*)(po)     = make_float4(o0x, o0y, o0z, o1x);
            *(float4*)(po + 4) = make_float4(o1y, o1z, o2x, o2y);
            *(float4*)(po + 8) = make_float4(o2z, o3x, o3y, o3z);
        }
    }
}

extern "C" void kernel_launch(void* const* d_in, const int* in_sizes, int n_in,
                              void* d_out, int out_size, void* d_ws, size_t ws_size,
                              hipStream_t stream) {
    const float* traj      = (const float*)d_in[0];
    const float* ref_pos   = (const float*)d_in[1];
    const int*   align_idx = (const int*)d_in[2];
    float*       out       = (float*)d_out;

    int B = in_sizes[0] / (NATOMS * 3);
    int grid = (B + FPB - 1) / FPB;
    align_kernel<<<grid, TPB, 0, stream>>>(traj, ref_pos, align_idx, out, B);
}